// Round 23
// baseline (64.318 us; speedup 1.0000x reference)
//
#include <hip/hip_runtime.h>

#define S_CACHE 32768
#define NQ 1024
#define D 128
#define KVB 32
#define TILES_TOTAL 1056
#define OBLK_BYTES 8192     // per (qg32, split): O^T packed u32 [chunk][32 q]
#define KV_TILE_BYTES 16384 // prepacked K frags (8 KB) + V frags (8 KB)
#define KV_BYTES ((size_t)TILES_TOTAL * KV_TILE_BYTES)  // 17,301,504

typedef float f32x4 __attribute__((ext_vector_type(4)));
typedef short s16x8 __attribute__((ext_vector_type(8)));
typedef int   i32x4 __attribute__((ext_vector_type(4)));

static __device__ __forceinline__ int cvtpk(float lo, float hi) {
  int r;
  asm("v_cvt_pk_bf16_f32 %0, %1, %2" : "=v"(r) : "v"(lo), "v"(hi));
  return r;
}
static __device__ __forceinline__ s16x8 frag4(int a, int b, int c, int d) {
  i32x4 t = {a, b, c, d};
  return __builtin_bit_cast(s16x8, t);
}
static __device__ __forceinline__ float bf2f(unsigned int b) {
  return __uint_as_float(b << 16);
}

// ---------------------------------------------------------------------------
// Prepack: K/V f32 -> bf16 in the exact MFMA-fragment image order.
// (Proven R5-R22 kernel, unchanged.)
// ---------------------------------------------------------------------------
__global__ __launch_bounds__(256) void mt_prepack(
    const float* __restrict__ Kc, const float* __restrict__ Vc,
    const float* __restrict__ knew, const float* __restrict__ vnew,
    unsigned char* __restrict__ kv)
{
  const int t = blockIdx.x;
  const int t32 = t * KVB;
  const float* Kb = (t32 < S_CACHE) ? Kc + (size_t)t32 * D
                                    : knew + (size_t)(t32 - S_CACHE) * D;
  const float* Vb = (t32 < S_CACHE) ? Vc + (size_t)t32 * D
                                    : vnew + (size_t)(t32 - S_CACHE) * D;
  unsigned char* outb = kv + (size_t)t * KV_TILE_BYTES;
#pragma unroll
  for (int rep = 0; rep < 4; ++rep) {
    const int id = rep * 256 + threadIdx.x;
    const int chunk = id >> 6;   // uniform per wave
    const int l  = id & 63;
    const int g  = l >> 4, qq = l & 15;
    i32x4 outv;
    if (chunk < 8) {
      const int h = chunk >> 2, c = chunk & 3;
      const int krow = 8 * (qq >> 2) + (qq & 3) + 4 * h;
      const float* src = Kb + (size_t)krow * D + 32 * c + 8 * g;
      f32x4 x0 = *(const f32x4*)src;
      f32x4 x1 = *(const f32x4*)(src + 4);
      outv = i32x4{cvtpk(x0[0], x0[1]), cvtpk(x0[2], x0[3]),
                   cvtpk(x1[0], x1[1]), cvtpk(x1[2], x1[3])};
    } else {
      const int dt = chunk - 8;
      float v[8];
#pragma unroll
      for (int i = 0; i < 8; ++i)
        v[i] = Vb[(size_t)(8 * g + i) * D + 16 * dt + qq];
      outv = i32x4{cvtpk(v[0], v[1]), cvtpk(v[2], v[3]),
                   cvtpk(v[4], v[5]), cvtpk(v[6], v[7])};
    }
    *(i32x4*)(outb + (size_t)chunk * 1024 + l * 16) = outv;
  }
}

// ---------------------------------------------------------------------------
// Main: R22 (PASSING, 52.4us) + ONE structural delta: 64 q PER WAVE (u=0..3
// instead of 0..1). Mechanism: K/V fragments are q-independent, so the same
// 16 dwordx4 loads per tile now feed 64 MFMA instead of 32 -- per-tile chain
// length is ~unchanged (u-streams are independent, more ILP) but work per
// exposed-latency window doubles, and total KV re-read traffic halves
// (16 qg64 waves/split instead of 32). Partial layout per 32-q half is
// byte-identical (qg32_eff = 2*qg64 + (u>>1)) -> combine untouched.
// __launch_bounds__(64) with NO min-wave arg (R13 squeeze class banned;
// allocator free to 512 VGPR, est ~300). Inert asm-"memory" fence kept
// (R21/R22-proven safe). No sched_barrier / multi-wave-no-barrier / LDS.
// XCD co-location: s=(n&7)+8*(n>>7), qg64=(n>>3)&15 (bijective, 768 blocks).
// ---------------------------------------------------------------------------
template <int KSPLIT>
__global__ __launch_bounds__(64) void mt_attn_main(
    const float* __restrict__ qp, const unsigned char* __restrict__ kv,
    unsigned char* __restrict__ ws)
{
  constexpr int TILES = TILES_TOTAL / KSPLIT;
  static_assert(TILES * KSPLIT == TILES_TOTAL, "KSPLIT must divide 1056");
  static_assert((KSPLIT & 7) == 0, "KSPLIT must be a multiple of 8");
  static_assert((TILES & 1) == 0, "parity-pair loop needs even TILES");

  const int lane = threadIdx.x & 63;
  const int g    = lane >> 4;
  const int qq   = lane & 15;

  const int n    = blockIdx.x;
  const int s    = (n & 7) + 8 * (n >> 7);   // split, pinned to XCD s%8
  const int qg64 = (n >> 3) & 15;            // 64-q group
  const int t_st = s * TILES;

  // ---- Q fragments (B-operand): lane holds Q[q][32c+8g+i], scaled ----
  const float QSCALE = 0.0883883476483184f * 1.4426950408889634f;  // 1/sqrt(128)*log2(e)
  s16x8 qf[4][4];
#pragma unroll
  for (int u = 0; u < 4; ++u) {
    const float* qrow = qp + (size_t)(qg64 * 64 + u * 16 + qq) * D + 8 * g;
#pragma unroll
    for (int c = 0; c < 4; ++c) {
      f32x4 x0 = *(const f32x4*)(qrow + 32 * c);
      f32x4 x1 = *(const f32x4*)(qrow + 32 * c + 4);
      qf[u][c] = frag4(cvtpk(x0[0] * QSCALE, x0[1] * QSCALE),
                       cvtpk(x0[2] * QSCALE, x0[3] * QSCALE),
                       cvtpk(x1[0] * QSCALE, x1[1] * QSCALE),
                       cvtpk(x1[2] * QSCALE, x1[3] * QSCALE));
    }
  }

  f32x4 oacc[4][8];
#pragma unroll
  for (int u = 0; u < 4; ++u)
#pragma unroll
    for (int dt = 0; dt < 8; ++dt) {
      f32x4 z = {0.f, 0.f, 0.f, 0.f};
      oacc[u][dt] = z;
    }
  float mrun[4] = {-1e30f, -1e30f, -1e30f, -1e30f};
  float lrun[4] = {0.f, 0.f, 0.f, 0.f};

  // wave-local fragment base: chunk c of tile t at +t*16K + c*1024 + lane*16
  const unsigned char* kvb = kv + (size_t)t_st * KV_TILE_BYTES + lane * 16;

  i32x4 kkA[8], kkB[8];  // K fragments, named double-buffer (static indices)
  i32x4 vv[8];           // V fragments, per-tile

  // ---- one tile: uses curk; prefetches K(t+1) into nxtk at the top ----
  auto step = [&](int t, i32x4 (&curk)[8], i32x4 (&nxtk)[8]) {
    const unsigned char* tb = kvb + (size_t)t * KV_TILE_BYTES;

    // V(t) first, then K(t+1).
#pragma unroll
    for (int c = 0; c < 8; ++c)
      vv[c] = *(const i32x4*)(tb + 8192 + c * 1024);
    if (t + 1 < TILES) {
#pragma unroll
      for (int c = 0; c < 8; ++c)
        nxtk[c] = *(const i32x4*)(tb + KV_TILE_BYTES + c * 1024);
    }
    asm volatile("" ::: "memory");  // R21/R22-proven: keep loads above compute

    // ---- QK^T (swapped): lane(g,qq) -> scores for q=qq, keys 8g+nn ----
    f32x4 sc[4][2];
#pragma unroll
    for (int u = 0; u < 4; ++u)
#pragma unroll
      for (int h = 0; h < 2; ++h) {
        f32x4 z = {0.f, 0.f, 0.f, 0.f};
        sc[u][h] = z;
      }
#pragma unroll
    for (int h = 0; h < 2; ++h)
#pragma unroll
      for (int c = 0; c < 4; ++c) {
        s16x8 kf = __builtin_bit_cast(s16x8, curk[h * 4 + c]);
#pragma unroll
        for (int u = 0; u < 4; ++u)
          sc[u][h] = __builtin_amdgcn_mfma_f32_16x16x32_bf16(kf, qf[u][c], sc[u][h], 0, 0, 0);
      }

    // ---- softmax (defer-max, base-2, lane-local rows) ----
    const int t32 = (t_st + t) * KVB;
    s16x8 pf[4];
#pragma unroll
    for (int u = 0; u < 4; ++u) {
      float sv[8];
#pragma unroll
      for (int h = 0; h < 2; ++h)
#pragma unroll
        for (int r = 0; r < 4; ++r)
          sv[4 * h + r] = sc[u][h][r];
      if (t32 >= S_CACHE) {  // causal mask (wave-uniform branch per tile)
        const int qglob = qg64 * 64 + u * 16 + qq;
#pragma unroll
        for (int nn = 0; nn < 8; ++nn) {
          const int key = t32 + 8 * g + nn;
          if (key - S_CACHE > qglob) sv[nn] = -1e30f;
        }
      }
      // lane-local max; NO shuffles on the common path (R22-proven guard).
      const float lmax = fmaxf(fmaxf(fmaxf(sv[0], sv[1]), fmaxf(sv[2], sv[3])),
                               fmaxf(fmaxf(sv[4], sv[5]), fmaxf(sv[6], sv[7])));
      if (!__all(lmax <= mrun[u] + 8.f)) {  // rare, wave-uniform
        float vmax = lmax;
        vmax = fmaxf(vmax, __shfl_xor(vmax, 16, 64));
        vmax = fmaxf(vmax, __shfl_xor(vmax, 32, 64));
        const float mnew = fmaxf(mrun[u], vmax);
        const float corr = exp2f(mrun[u] - mnew);
        lrun[u] *= corr;
#pragma unroll
        for (int dt = 0; dt < 8; ++dt) oacc[u][dt] *= corr;
        mrun[u] = mnew;
      }
      float p[8], rs = 0.f;
#pragma unroll
      for (int nn = 0; nn < 8; ++nn) {
        p[nn] = exp2f(sv[nn] - mrun[u]);
        rs += p[nn];
      }
      lrun[u] += rs;  // per-lane partial; butterfly in epilogue
      pf[u] = frag4(cvtpk(p[0], p[1]), cvtpk(p[2], p[3]),
                    cvtpk(p[4], p[5]), cvtpk(p[6], p[7]));
    }

    // ---- PV (swapped): O^T += V^T @ P^T ----
#pragma unroll
    for (int dt = 0; dt < 8; ++dt) {
      s16x8 vf = __builtin_bit_cast(s16x8, vv[dt]);
#pragma unroll
      for (int u = 0; u < 4; ++u)
        oacc[u][dt] = __builtin_amdgcn_mfma_f32_16x16x32_bf16(vf, pf[u], oacc[u][dt], 0, 0, 0);
    }
  };

  // preload K(0) into A
#pragma unroll
  for (int c = 0; c < 8; ++c)
    kkA[c] = *(const i32x4*)(kvb + c * 1024);

  for (int tp = 0; tp < TILES / 2; ++tp) {
    step(2 * tp,     kkA, kkB);
    step(2 * tp + 1, kkB, kkA);
  }

  // ---- epilogue: cross-lane l reduction over the 4 g-groups ----
#pragma unroll
  for (int u = 0; u < 4; ++u) {
    lrun[u] += __shfl_xor(lrun[u], 16, 64);
    lrun[u] += __shfl_xor(lrun[u], 32, 64);
  }

  // ---- partials: packed u32 O^T (full-line stores) + dense m,l ----
  // per 32-q half: qg32_eff = 2*qg64 + (u>>1); within-half index u&1.
  unsigned char* wsp = ws + KV_BYTES;
  float* m_ws = (float*)(wsp + (size_t)32 * KSPLIT * OBLK_BYTES);
  float* l_ws = m_ws + (size_t)NQ * KSPLIT;
#pragma unroll
  for (int u = 0; u < 4; ++u) {
    const int qg32e = 2 * qg64 + (u >> 1);
    const int uh = u & 1;
    unsigned int* pO =
        (unsigned int*)(wsp + (size_t)(qg32e * KSPLIT + s) * OBLK_BYTES);
#pragma unroll
    for (int dt = 0; dt < 8; ++dt)
#pragma unroll
      for (int r2 = 0; r2 < 2; ++r2)
        pO[(8 * dt + 2 * g + r2) * 32 + uh * 16 + qq] =
            (unsigned int)cvtpk(oacc[u][dt][2 * r2], oacc[u][dt][2 * r2 + 1]);
    if (g == 0) {
      const int q = qg64 * 64 + u * 16 + qq;
      m_ws[(size_t)q * KSPLIT + s] = mrun[u];
      l_ws[(size_t)q * KSPLIT + s] = lrun[u];
    }
  }
}

// ---------------------------------------------------------------------------
// Combine (proven, with m). One thread per (q, dv), full unroll. UNCHANGED.
// ---------------------------------------------------------------------------
template <int S>
__global__ __launch_bounds__(256) void mt_attn_combine(
    const unsigned char* __restrict__ ws, float* __restrict__ out)
{
  const int t  = blockIdx.x * 256 + threadIdx.x;  // 131072 total
  const int ql = t & 31;
  const int dv = (t >> 5) & 127;
  const int qg = t >> 12;
  const int q  = qg * 32 + ql;

  const unsigned char* wsp = ws + KV_BYTES;
  const float* m_ws = (const float*)(wsp + (size_t)32 * S * OBLK_BYTES);
  const float* l_ws = m_ws + (size_t)NQ * S;
  const float* mrow = m_ws + (size_t)q * S;
  const float* lrow = l_ws + (size_t)q * S;

  float mg = -1e30f;
#pragma unroll
  for (int s4 = 0; s4 < S / 4; ++s4) {
    f32x4 m4 = *(const f32x4*)(mrow + 4 * s4);
    mg = fmaxf(mg, fmaxf(fmaxf(m4[0], m4[1]), fmaxf(m4[2], m4[3])));
  }
  float L = 0.f;
#pragma unroll
  for (int s4 = 0; s4 < S / 4; ++s4) {
    f32x4 m4 = *(const f32x4*)(mrow + 4 * s4);
    f32x4 l4 = *(const f32x4*)(lrow + 4 * s4);
    L += l4[0] * exp2f(m4[0] - mg) + l4[1] * exp2f(m4[1] - mg) +
         l4[2] * exp2f(m4[2] - mg) + l4[3] * exp2f(m4[3] - mg);
  }
  // packed-O read: dv -> (dt, g, r); word (8dt+2g+(r>>1))*32 + ql, half r&1
  const int dt = dv >> 4, g2 = (dv >> 2) & 3, r = dv & 3;
  const int word = (8 * dt + 2 * g2 + (r >> 1)) * 32 + ql;
  const int sh = (r & 1) * 16;
  const unsigned int* base =
      (const unsigned int*)(wsp + (size_t)qg * S * OBLK_BYTES) + word;
  float acc = 0.f;
#pragma unroll
  for (int s = 0; s < S; ++s) {
    const float wgt = exp2f(mrow[s] - mg);
    acc += wgt * bf2f((base[(size_t)s * (OBLK_BYTES / 4)] >> sh) & 0xffffu);
  }
  out[(size_t)q * D + dv] = acc / L;
}

extern "C" void kernel_launch(void* const* d_in, const int* in_sizes, int n_in,
                              void* d_out, int out_size, void* d_ws, size_t ws_size,
                              hipStream_t stream)
{
  const float* qp = (const float*)d_in[0];
  const float* kp = (const float*)d_in[1];
  const float* vp = (const float*)d_in[2];
  const float* Kc = (const float*)d_in[3];
  const float* Vc = (const float*)d_in[4];
  float* out = (float*)d_out;
  unsigned char* ws = (unsigned char*)d_ws;

  // ws: [0, KV_BYTES) prepacked KV | O partials (32*K*8KB) | m,l (2*NQ*K*4)
  static const int cands[] = {48, 24, 16, 8};
  int ksplit = 8;
  for (int i = 0; i < 4; ++i) {
    size_t need = KV_BYTES + (size_t)cands[i] * (32 * OBLK_BYTES + 8 * NQ);
    if (need <= ws_size) { ksplit = cands[i]; break; }
  }

  mt_prepack<<<dim3(TILES_TOTAL), dim3(256), 0, stream>>>(Kc, Vc, kp, vp, ws);

  const dim3 cgrid((NQ * D) / 256), cblk(256);
  switch (ksplit) {
    case 48:
      mt_attn_main<48><<<dim3(16 * 48), dim3(64), 0, stream>>>(qp, ws, ws);
      mt_attn_combine<48><<<cgrid, cblk, 0, stream>>>(ws, out);
      break;
    case 24:
      mt_attn_main<24><<<dim3(16 * 24), dim3(64), 0, stream>>>(qp, ws, ws);
      mt_attn_combine<24><<<cgrid, cblk, 0, stream>>>(ws, out);
      break;
    case 16:
      mt_attn_main<16><<<dim3(16 * 16), dim3(64), 0, stream>>>(qp, ws, ws);
      mt_attn_combine<16><<<cgrid, cblk, 0, stream>>>(ws, out);
      break;
    default:
      mt_attn_main<8><<<dim3(16 * 8), dim3(64), 0, stream>>>(qp, ws, ws);
      mt_attn_combine<8><<<cgrid, cblk, 0, stream>>>(ws, out);
      break;
  }
}

// Round 24
// 51.941 us; speedup vs baseline: 1.2383x; 1.2383x over previous
//
#include <hip/hip_runtime.h>

#define S_CACHE 32768
#define NQ 1024
#define D 128
#define KVB 32
#define TILES_TOTAL 1056
#define OBLK_BYTES 8192     // per (qg32, split): O^T packed u32 [chunk][32 q]
#define KV_TILE_BYTES 16384 // prepacked K frags (8 KB) + V frags (8 KB)
#define KV_BYTES ((size_t)TILES_TOTAL * KV_TILE_BYTES)  // 17,301,504

typedef float f32x4 __attribute__((ext_vector_type(4)));
typedef short s16x8 __attribute__((ext_vector_type(8)));
typedef int   i32x4 __attribute__((ext_vector_type(4)));

static __device__ __forceinline__ int cvtpk(float lo, float hi) {
  int r;
  asm("v_cvt_pk_bf16_f32 %0, %1, %2" : "=v"(r) : "v"(lo), "v"(hi));
  return r;
}
static __device__ __forceinline__ s16x8 frag4(int a, int b, int c, int d) {
  i32x4 t = {a, b, c, d};
  return __builtin_bit_cast(s16x8, t);
}
static __device__ __forceinline__ float bf2f(unsigned int b) {
  return __uint_as_float(b << 16);
}

// ---------------------------------------------------------------------------
// Prepack: K/V f32 -> bf16 in the exact MFMA-fragment image order.
// ---------------------------------------------------------------------------
__global__ __launch_bounds__(256) void mt_prepack(
    const float* __restrict__ Kc, const float* __restrict__ Vc,
    const float* __restrict__ knew, const float* __restrict__ vnew,
    unsigned char* __restrict__ kv)
{
  const int t = blockIdx.x;
  const int t32 = t * KVB;
  const float* Kb = (t32 < S_CACHE) ? Kc + (size_t)t32 * D
                                    : knew + (size_t)(t32 - S_CACHE) * D;
  const float* Vb = (t32 < S_CACHE) ? Vc + (size_t)t32 * D
                                    : vnew + (size_t)(t32 - S_CACHE) * D;
  unsigned char* outb = kv + (size_t)t * KV_TILE_BYTES;
#pragma unroll
  for (int rep = 0; rep < 4; ++rep) {
    const int id = rep * 256 + threadIdx.x;
    const int chunk = id >> 6;   // uniform per wave
    const int l  = id & 63;
    const int g  = l >> 4, qq = l & 15;
    i32x4 outv;
    if (chunk < 8) {
      const int h = chunk >> 2, c = chunk & 3;
      const int krow = 8 * (qq >> 2) + (qq & 3) + 4 * h;
      const float* src = Kb + (size_t)krow * D + 32 * c + 8 * g;
      f32x4 x0 = *(const f32x4*)src;
      f32x4 x1 = *(const f32x4*)(src + 4);
      outv = i32x4{cvtpk(x0[0], x0[1]), cvtpk(x0[2], x0[3]),
                   cvtpk(x1[0], x1[1]), cvtpk(x1[2], x1[3])};
    } else {
      const int dt = chunk - 8;
      float v[8];
#pragma unroll
      for (int i = 0; i < 8; ++i)
        v[i] = Vb[(size_t)(8 * g + i) * D + 16 * dt + qq];
      outv = i32x4{cvtpk(v[0], v[1]), cvtpk(v[2], v[3]),
                   cvtpk(v[4], v[5]), cvtpk(v[6], v[7])};
    }
    *(i32x4*)(outb + (size_t)chunk * 1024 + l * 16) = outv;
  }
}

// ---------------------------------------------------------------------------
// Main (R22, best passing: 52.4us total). Single-wave blocks, register-direct
// KV from the prepacked fragment image, shuffle-free defer-max softmax.
// R23's 64q/wave REVERTED: VGPR hit the 256 cap, occupancy 6.5%, main +13us.
// BANNED (measured): sched_barrier in this body (R20), 4-wave WG without
// s_barrier (R18/R19), launch_bounds reg-squeeze (R13), small-block LDS
// (R16), fatter waves q- or K-axis (R23/register arithmetic).
// XCD co-location: s=(n&7)+8*(n>>8), qg32=(n>>3)&31 (bijective).
// ---------------------------------------------------------------------------
template <int KSPLIT>
__global__ __launch_bounds__(64, 2) void mt_attn_main(
    const float* __restrict__ qp, const unsigned char* __restrict__ kv,
    unsigned char* __restrict__ ws)
{
  constexpr int TILES = TILES_TOTAL / KSPLIT;
  static_assert(TILES * KSPLIT == TILES_TOTAL, "KSPLIT must divide 1056");
  static_assert((KSPLIT & 7) == 0, "KSPLIT must be a multiple of 8");
  static_assert((TILES & 1) == 0, "parity-pair loop needs even TILES");

  const int lane = threadIdx.x & 63;
  const int g    = lane >> 4;
  const int qq   = lane & 15;

  const int n    = blockIdx.x;
  const int s    = (n & 7) + 8 * (n >> 8);   // split, pinned to XCD s%8
  const int qg32 = (n >> 3) & 31;            // 32-q group
  const int t_st = s * TILES;

  // ---- Q fragments (B-operand): lane holds Q[q][32c+8g+i], scaled ----
  const float QSCALE = 0.0883883476483184f * 1.4426950408889634f;  // 1/sqrt(128)*log2(e)
  s16x8 qf[2][4];
#pragma unroll
  for (int u = 0; u < 2; ++u) {
    const float* qrow = qp + (size_t)(qg32 * 32 + u * 16 + qq) * D + 8 * g;
#pragma unroll
    for (int c = 0; c < 4; ++c) {
      f32x4 x0 = *(const f32x4*)(qrow + 32 * c);
      f32x4 x1 = *(const f32x4*)(qrow + 32 * c + 4);
      qf[u][c] = frag4(cvtpk(x0[0] * QSCALE, x0[1] * QSCALE),
                       cvtpk(x0[2] * QSCALE, x0[3] * QSCALE),
                       cvtpk(x1[0] * QSCALE, x1[1] * QSCALE),
                       cvtpk(x1[2] * QSCALE, x1[3] * QSCALE));
    }
  }

  f32x4 oacc[2][8];
#pragma unroll
  for (int u = 0; u < 2; ++u)
#pragma unroll
    for (int dt = 0; dt < 8; ++dt) {
      f32x4 z = {0.f, 0.f, 0.f, 0.f};
      oacc[u][dt] = z;
    }
  float mrun[2] = {-1e30f, -1e30f};
  float lrun[2] = {0.f, 0.f};

  // wave-local fragment base: chunk c of tile t at +t*16K + c*1024 + lane*16
  const unsigned char* kvb = kv + (size_t)t_st * KV_TILE_BYTES + lane * 16;

  i32x4 kkA[8], kkB[8];  // K fragments, named double-buffer (static indices)
  i32x4 vv[8];           // V fragments, per-tile

  // ---- one tile: uses curk; prefetches K(t+1) into nxtk at the top ----
  auto step = [&](int t, i32x4 (&curk)[8], i32x4 (&nxtk)[8]) {
    const unsigned char* tb = kvb + (size_t)t * KV_TILE_BYTES;

    // V(t) first, then K(t+1).
#pragma unroll
    for (int c = 0; c < 8; ++c)
      vv[c] = *(const i32x4*)(tb + 8192 + c * 1024);
    if (t + 1 < TILES) {
#pragma unroll
      for (int c = 0; c < 8; ++c)
        nxtk[c] = *(const i32x4*)(tb + KV_TILE_BYTES + c * 1024);
    }
    asm volatile("" ::: "memory");  // proven-safe: keep loads above compute

    // ---- QK^T (swapped): lane(g,qq) -> scores for q=qq, keys 8g+nn ----
    f32x4 sc[2][2];
#pragma unroll
    for (int u = 0; u < 2; ++u)
#pragma unroll
      for (int h = 0; h < 2; ++h) {
        f32x4 z = {0.f, 0.f, 0.f, 0.f};
        sc[u][h] = z;
      }
#pragma unroll
    for (int h = 0; h < 2; ++h)
#pragma unroll
      for (int c = 0; c < 4; ++c) {
        s16x8 kf = __builtin_bit_cast(s16x8, curk[h * 4 + c]);
        sc[0][h] = __builtin_amdgcn_mfma_f32_16x16x32_bf16(kf, qf[0][c], sc[0][h], 0, 0, 0);
        sc[1][h] = __builtin_amdgcn_mfma_f32_16x16x32_bf16(kf, qf[1][c], sc[1][h], 0, 0, 0);
      }

    // ---- softmax (defer-max, base-2, lane-local rows) ----
    const int t32 = (t_st + t) * KVB;
    s16x8 pf[2];
#pragma unroll
    for (int u = 0; u < 2; ++u) {
      float sv[8];
#pragma unroll
      for (int h = 0; h < 2; ++h)
#pragma unroll
        for (int r = 0; r < 4; ++r)
          sv[4 * h + r] = sc[u][h][r];
      if (t32 >= S_CACHE) {  // causal mask (wave-uniform branch per tile)
        const int qglob = qg32 * 32 + u * 16 + qq;
#pragma unroll
        for (int nn = 0; nn < 8; ++nn) {
          const int key = t32 + 8 * g + nn;
          if (key - S_CACHE > qglob) sv[nn] = -1e30f;
        }
      }
      // lane-local 8-key max; NO shuffles on the common path. Trigger
      // equivalence: row-max > mrun+8  <=>  some lane of that row has
      // local-max > mrun+8, and __all() is the wave-wide reduction.
      const float lmax = fmaxf(fmaxf(fmaxf(sv[0], sv[1]), fmaxf(sv[2], sv[3])),
                               fmaxf(fmaxf(sv[4], sv[5]), fmaxf(sv[6], sv[7])));
      if (!__all(lmax <= mrun[u] + 8.f)) {  // rare, wave-uniform
        float vmax = lmax;                  // true row max (lanes qq+16g)
        vmax = fmaxf(vmax, __shfl_xor(vmax, 16, 64));
        vmax = fmaxf(vmax, __shfl_xor(vmax, 32, 64));
        const float mnew = fmaxf(mrun[u], vmax);
        const float corr = exp2f(mrun[u] - mnew);
        lrun[u] *= corr;
#pragma unroll
        for (int dt = 0; dt < 8; ++dt) oacc[u][dt] *= corr;
        mrun[u] = mnew;
      }
      float p[8], rs = 0.f;
#pragma unroll
      for (int nn = 0; nn < 8; ++nn) {
        p[nn] = exp2f(sv[nn] - mrun[u]);
        rs += p[nn];
      }
      lrun[u] += rs;  // per-lane partial; butterfly in epilogue
      pf[u] = frag4(cvtpk(p[0], p[1]), cvtpk(p[2], p[3]),
                    cvtpk(p[4], p[5]), cvtpk(p[6], p[7]));
    }

    // ---- PV (swapped): O^T += V^T @ P^T ----
#pragma unroll
    for (int dt = 0; dt < 8; ++dt) {
      s16x8 vf = __builtin_bit_cast(s16x8, vv[dt]);
      oacc[0][dt] = __builtin_amdgcn_mfma_f32_16x16x32_bf16(vf, pf[0], oacc[0][dt], 0, 0, 0);
      oacc[1][dt] = __builtin_amdgcn_mfma_f32_16x16x32_bf16(vf, pf[1], oacc[1][dt], 0, 0, 0);
    }
  };

  // preload K(0) into A
#pragma unroll
  for (int c = 0; c < 8; ++c)
    kkA[c] = *(const i32x4*)(kvb + c * 1024);

  for (int tp = 0; tp < TILES / 2; ++tp) {
    step(2 * tp,     kkA, kkB);
    step(2 * tp + 1, kkB, kkA);
  }

  // ---- epilogue: cross-lane l reduction over the 4 g-groups ----
#pragma unroll
  for (int u = 0; u < 2; ++u) {
    lrun[u] += __shfl_xor(lrun[u], 16, 64);
    lrun[u] += __shfl_xor(lrun[u], 32, 64);
  }

  // ---- partials: packed u32 O^T (full-line stores) + dense m,l ----
  unsigned char* wsp = ws + KV_BYTES;
  unsigned int* pO = (unsigned int*)(wsp + (size_t)(qg32 * KSPLIT + s) * OBLK_BYTES);
  float* m_ws = (float*)(wsp + (size_t)32 * KSPLIT * OBLK_BYTES);
  float* l_ws = m_ws + (size_t)NQ * KSPLIT;
#pragma unroll
  for (int u = 0; u < 2; ++u) {
#pragma unroll
    for (int dt = 0; dt < 8; ++dt)
#pragma unroll
      for (int r2 = 0; r2 < 2; ++r2)
        pO[(8 * dt + 2 * g + r2) * 32 + u * 16 + qq] =
            (unsigned int)cvtpk(oacc[u][dt][2 * r2], oacc[u][dt][2 * r2 + 1]);
    if (g == 0) {
      const int q = qg32 * 32 + u * 16 + qq;
      m_ws[(size_t)q * KSPLIT + s] = mrun[u];
      l_ws[(size_t)q * KSPLIT + s] = lrun[u];
    }
  }
}

// ---------------------------------------------------------------------------
// Combine (proven, with m). One thread per (q, dv), full unroll.
// ---------------------------------------------------------------------------
template <int S>
__global__ __launch_bounds__(256) void mt_attn_combine(
    const unsigned char* __restrict__ ws, float* __restrict__ out)
{
  const int t  = blockIdx.x * 256 + threadIdx.x;  // 131072 total
  const int ql = t & 31;
  const int dv = (t >> 5) & 127;
  const int qg = t >> 12;
  const int q  = qg * 32 + ql;

  const unsigned char* wsp = ws + KV_BYTES;
  const float* m_ws = (const float*)(wsp + (size_t)32 * S * OBLK_BYTES);
  const float* l_ws = m_ws + (size_t)NQ * S;
  const float* mrow = m_ws + (size_t)q * S;
  const float* lrow = l_ws + (size_t)q * S;

  float mg = -1e30f;
#pragma unroll
  for (int s4 = 0; s4 < S / 4; ++s4) {
    f32x4 m4 = *(const f32x4*)(mrow + 4 * s4);
    mg = fmaxf(mg, fmaxf(fmaxf(m4[0], m4[1]), fmaxf(m4[2], m4[3])));
  }
  float L = 0.f;
#pragma unroll
  for (int s4 = 0; s4 < S / 4; ++s4) {
    f32x4 m4 = *(const f32x4*)(mrow + 4 * s4);
    f32x4 l4 = *(const f32x4*)(lrow + 4 * s4);
    L += l4[0] * exp2f(m4[0] - mg) + l4[1] * exp2f(m4[1] - mg) +
         l4[2] * exp2f(m4[2] - mg) + l4[3] * exp2f(m4[3] - mg);
  }
  // packed-O read: dv -> (dt, g, r); word (8dt+2g+(r>>1))*32 + ql, half r&1
  const int dt = dv >> 4, g2 = (dv >> 2) & 3, r = dv & 3;
  const int word = (8 * dt + 2 * g2 + (r >> 1)) * 32 + ql;
  const int sh = (r & 1) * 16;
  const unsigned int* base =
      (const unsigned int*)(wsp + (size_t)qg * S * OBLK_BYTES) + word;
  float acc = 0.f;
#pragma unroll
  for (int s = 0; s < S; ++s) {
    const float wgt = exp2f(mrow[s] - mg);
    acc += wgt * bf2f((base[(size_t)s * (OBLK_BYTES / 4)] >> sh) & 0xffffu);
  }
  out[(size_t)q * D + dv] = acc / L;
}

extern "C" void kernel_launch(void* const* d_in, const int* in_sizes, int n_in,
                              void* d_out, int out_size, void* d_ws, size_t ws_size,
                              hipStream_t stream)
{
  const float* qp = (const float*)d_in[0];
  const float* kp = (const float*)d_in[1];
  const float* vp = (const float*)d_in[2];
  const float* Kc = (const float*)d_in[3];
  const float* Vc = (const float*)d_in[4];
  float* out = (float*)d_out;
  unsigned char* ws = (unsigned char*)d_ws;

  // ws: [0, KV_BYTES) prepacked KV | O partials (32*K*8KB) | m,l (2*NQ*K*4)
  static const int cands[] = {48, 24, 16, 8};
  int ksplit = 8;
  for (int i = 0; i < 4; ++i) {
    size_t need = KV_BYTES + (size_t)cands[i] * (32 * OBLK_BYTES + 8 * NQ);
    if (need <= ws_size) { ksplit = cands[i]; break; }
  }

  mt_prepack<<<dim3(TILES_TOTAL), dim3(256), 0, stream>>>(Kc, Vc, kp, vp, ws);

  const dim3 cgrid((NQ * D) / 256), cblk(256);
  switch (ksplit) {
    case 48:
      mt_attn_main<48><<<dim3(32 * 48), dim3(64), 0, stream>>>(qp, ws, ws);
      mt_attn_combine<48><<<cgrid, cblk, 0, stream>>>(ws, out);
      break;
    case 24:
      mt_attn_main<24><<<dim3(32 * 24), dim3(64), 0, stream>>>(qp, ws, ws);
      mt_attn_combine<24><<<cgrid, cblk, 0, stream>>>(ws, out);
      break;
    case 16:
      mt_attn_main<16><<<dim3(32 * 16), dim3(64), 0, stream>>>(qp, ws, ws);
      mt_attn_combine<16><<<cgrid, cblk, 0, stream>>>(ws, out);
      break;
    default:
      mt_attn_main<8><<<dim3(32 * 8), dim3(64), 0, stream>>>(qp, ws, ws);
      mt_attn_combine<8><<<cgrid, cblk, 0, stream>>>(ws, out);
      break;
  }
}